// Round 6
// baseline (456.932 us; speedup 1.0000x reference)
//
#include <hip/hip_runtime.h>
#include <hip/hip_bf16.h>

#define N_NODES 100000
#define N_EDGES 3200000
#define D 256
#define SHIFT 9            // 512 rows per bucket
#define NB 196             // ceil(100000 / 512)
#define EPB 4096           // edges per split block
#define NSPLIT 782         // ceil(N_EDGES / EPB)
#define NGEMM 1563         // ceil(N_NODES / 64)

typedef __attribute__((ext_vector_type(8))) short short8;
typedef __attribute__((ext_vector_type(4))) float f32x4;

__device__ inline short bfbits(float x) {
    __hip_bfloat16 h = __float2bfloat16(x);
    return __builtin_bit_cast(short, h);
}

__device__ inline short8 load_cvt8(const float* __restrict__ p) {
    float4 a = *(const float4*)p;
    float4 b = *(const float4*)(p + 4);
    short8 r;
    r[0] = bfbits(a.x); r[1] = bfbits(a.y); r[2] = bfbits(a.z); r[3] = bfbits(a.w);
    r[4] = bfbits(b.x); r[5] = bfbits(b.y); r[6] = bfbits(b.z); r[7] = bfbits(b.w);
    return r;
}

// 256-thread block exclusive scan (wave shfl + 4 wave sums). wsum = LDS int[4].
__device__ inline int block_excl_scan_256(int c, int* wsum, int& total) {
    const int lane = threadIdx.x & 63, wid = threadIdx.x >> 6;
    int v = c;
    #pragma unroll
    for (int off = 1; off < 64; off <<= 1) {
        int u = __shfl_up(v, off);
        if (lane >= off) v += u;
    }
    if (lane == 63) wsum[wid] = v;
    __syncthreads();
    int w0 = wsum[0], w1 = wsum[1], w2 = wsum[2], w3 = wsum[3];
    total = w0 + w1 + w2 + w3;
    int wex = (wid > 0 ? w0 : 0) + (wid > 1 ? w1 : 0) + (wid > 2 ? w2 : 0);
    return wex + v - c;
}

// ===================== 1) global bucket histogram (LDS-staged) =============
__global__ __launch_bounds__(256) void bucket_hist(
    const int* __restrict__ rows, int* __restrict__ gcnt, int nE)
{
    __shared__ int h[NB];
    for (int i = threadIdx.x; i < NB; i += 256) h[i] = 0;
    __syncthreads();
    for (int e = blockIdx.x * 256 + threadIdx.x; e < nE; e += gridDim.x * 256)
        atomicAdd(&h[rows[e] >> SHIFT], 1);
    __syncthreads();
    for (int i = threadIdx.x; i < NB; i += 256)
        if (h[i]) atomicAdd(&gcnt[i], h[i]);
}

// ===================== 2) bucket scan (one block) ==========================
__global__ __launch_bounds__(256) void bucket_scan(
    const int* __restrict__ gcnt, int* __restrict__ bbase,
    int* __restrict__ gcursor, int* __restrict__ row_ptr)
{
    __shared__ int wsum[4];
    int c = (threadIdx.x < NB) ? gcnt[threadIdx.x] : 0;
    int total;
    int ex = block_excl_scan_256(c, wsum, total);
    if (threadIdx.x < NB) { bbase[threadIdx.x] = ex; gcursor[threadIdx.x] = ex; }
    if (threadIdx.x == 0) { bbase[NB] = total; row_ptr[N_NODES] = total; }
}

// ============== 3) merged: bucket split  ||  GEMM Y = X@W^T ================
// Blocks [0, NSPLIT): split EPB edges into bucket-grouped bcv (packed
// (row_local<<17)|col, val). Per-block bucket reservation keeps the global
// writes line-dense. Blocks [NSPLIT, NSPLIT+NGEMM): bf16 MFMA GEMM producing
// Y (64 rows per block, 4 waves = 4 col-panels of 64).
__global__ __launch_bounds__(256) void split_gemm(
    const int* __restrict__ rows, const int* __restrict__ cols,
    const float* __restrict__ vals, int* __restrict__ gcursor,
    int2* __restrict__ bcv,
    const float* __restrict__ X, const float* __restrict__ W,
    unsigned short* __restrict__ Y, int nE)
{
    if (blockIdx.x < NSPLIT) {
        // ----------------------------- split -------------------------------
        __shared__ int cnt[256];
        __shared__ int posp[256];
        const int t  = threadIdx.x;
        const int e0 = blockIdx.x * EPB;

        cnt[t] = 0;
        __syncthreads();

        int  myb[16];
        int2 mycv[16];
        #pragma unroll
        for (int k = 0; k < 16; ++k) {
            int e = e0 + k * 256 + t;
            if (e < nE) {
                int r = rows[e];
                myb[k]  = r >> SHIFT;
                mycv[k] = make_int2(((r & 511) << 17) | cols[e],
                                    __float_as_int(vals[e]));
                atomicAdd(&cnt[myb[k]], 1);
            } else {
                myb[k] = -1;
            }
        }
        __syncthreads();
        if (t < NB) {
            int c = cnt[t];
            posp[t] = c ? atomicAdd(&gcursor[t], c) : 0;
        }
        __syncthreads();
        #pragma unroll
        for (int k = 0; k < 16; ++k) {
            if (myb[k] >= 0) {
                int p = atomicAdd(&posp[myb[k]], 1);
                bcv[p] = mycv[k];
            }
        }
    } else {
        // ----------------------------- GEMM --------------------------------
        const int bid  = blockIdx.x - NSPLIT;
        const int wid  = threadIdx.x >> 6;
        const int lane = threadIdx.x & 63;
        const int m0   = bid * 64;
        const int n0   = wid * 64;
        const int lr   = lane & 15;
        const int ko   = (lane >> 4) * 8;
        const int M    = N_NODES;

        f32x4 acc[4][4] = {};

        #pragma unroll
        for (int k0 = 0; k0 < 256; k0 += 32) {
            short8 bfrag[4], afrag[4];
            #pragma unroll
            for (int j = 0; j < 4; ++j)
                bfrag[j] = load_cvt8(W + (size_t)(n0 + j * 16 + lr) * 256 + k0 + ko);
            #pragma unroll
            for (int i = 0; i < 4; ++i) {
                int r = m0 + i * 16 + lr;
                if (r > M - 1) r = M - 1;
                afrag[i] = load_cvt8(X + (size_t)r * 256 + k0 + ko);
            }
            #pragma unroll
            for (int i = 0; i < 4; ++i)
                #pragma unroll
                for (int j = 0; j < 4; ++j)
                    acc[i][j] = __builtin_amdgcn_mfma_f32_16x16x32_bf16(
                        afrag[i], bfrag[j], acc[i][j], 0, 0, 0);
        }

        #pragma unroll
        for (int i = 0; i < 4; ++i) {
            int rbase = m0 + i * 16 + (lane >> 4) * 4;
            #pragma unroll
            for (int rr = 0; rr < 4; ++rr) {
                int r = rbase + rr;
                if (r < M) {
                    #pragma unroll
                    for (int j = 0; j < 4; ++j)
                        Y[(size_t)r * 256 + n0 + j * 16 + lr] =
                            (unsigned short)bfbits(acc[i][j][rr]);
                }
            }
        }
    }
}

// ===================== 4) per-bucket counting sort -> CSR ==================
__global__ __launch_bounds__(256) void bucket_to_csr(
    const int* __restrict__ bbase, const int2* __restrict__ bcv,
    int* __restrict__ row_ptr, int2* __restrict__ cedge)
{
    __shared__ int hist[512];
    __shared__ int cur[512];
    __shared__ int wsum[4];
    const int t  = threadIdx.x;
    const int b  = blockIdx.x;
    const int r0 = b << SHIFT;
    const int s  = bbase[b], e = bbase[b + 1];

    hist[t] = 0; hist[t + 256] = 0;
    __syncthreads();
    for (int j = s + t; j < e; j += 256)
        atomicAdd(&hist[(unsigned)bcv[j].x >> 17], 1);
    __syncthreads();

    int c0 = hist[2 * t], c1 = hist[2 * t + 1];
    int total;
    int ex = block_excl_scan_256(c0 + c1, wsum, total);
    cur[2 * t]     = s + ex;
    cur[2 * t + 1] = s + ex + c0;
    int r = r0 + 2 * t;
    if (r     < N_NODES) row_ptr[r]     = s + ex;
    if (r + 1 < N_NODES) row_ptr[r + 1] = s + ex + c0;
    __syncthreads();

    for (int j = s + t; j < e; j += 256) {
        int2 q = bcv[j];
        int rl = (unsigned)q.x >> 17;
        int p = atomicAdd(&cur[rl], 1);
        cedge[p] = make_int2(q.x & 0x1FFFF, q.y);
    }
}

// =================== 5) Gather SpMM:  H = relu(A @ Y) ======================
__global__ __launch_bounds__(256) void spmm_gather_relu(
    const unsigned short* __restrict__ Y,
    const int* __restrict__ row_ptr,
    const int2* __restrict__ cedge,
    float* __restrict__ H)
{
    int row  = blockIdx.x * 4 + (threadIdx.x >> 6);
    int lane = threadIdx.x & 63;
    if (row >= N_NODES) return;
    int s = row_ptr[row];
    int e = row_ptr[row + 1];

    float4 acc = make_float4(0.f, 0.f, 0.f, 0.f);
    const int fo = lane * 4;

    for (int base = s; base < e; base += 64) {
        int idx = base + lane;
        int2 q = make_int2(0, 0);
        if (idx < e) q = cedge[idx];
        int cnt = min(64, e - base);
        int j = 0;
        for (; j + 4 <= cnt; j += 4) {
            int c0 = __builtin_amdgcn_readfirstlane(__shfl(q.x, j));
            int c1 = __builtin_amdgcn_readfirstlane(__shfl(q.x, j + 1));
            int c2 = __builtin_amdgcn_readfirstlane(__shfl(q.x, j + 2));
            int c3 = __builtin_amdgcn_readfirstlane(__shfl(q.x, j + 3));
            float v0 = __int_as_float(__builtin_amdgcn_readfirstlane(__shfl(q.y, j)));
            float v1 = __int_as_float(__builtin_amdgcn_readfirstlane(__shfl(q.y, j + 1)));
            float v2 = __int_as_float(__builtin_amdgcn_readfirstlane(__shfl(q.y, j + 2)));
            float v3 = __int_as_float(__builtin_amdgcn_readfirstlane(__shfl(q.y, j + 3)));
            ushort4 y0 = *(const ushort4*)(Y + (size_t)c0 * 256 + fo);
            ushort4 y1 = *(const ushort4*)(Y + (size_t)c1 * 256 + fo);
            ushort4 y2 = *(const ushort4*)(Y + (size_t)c2 * 256 + fo);
            ushort4 y3 = *(const ushort4*)(Y + (size_t)c3 * 256 + fo);
            acc.x += __uint_as_float((unsigned)y0.x << 16) * v0;
            acc.y += __uint_as_float((unsigned)y0.y << 16) * v0;
            acc.z += __uint_as_float((unsigned)y0.z << 16) * v0;
            acc.w += __uint_as_float((unsigned)y0.w << 16) * v0;
            acc.x += __uint_as_float((unsigned)y1.x << 16) * v1;
            acc.y += __uint_as_float((unsigned)y1.y << 16) * v1;
            acc.z += __uint_as_float((unsigned)y1.z << 16) * v1;
            acc.w += __uint_as_float((unsigned)y1.w << 16) * v1;
            acc.x += __uint_as_float((unsigned)y2.x << 16) * v2;
            acc.y += __uint_as_float((unsigned)y2.y << 16) * v2;
            acc.z += __uint_as_float((unsigned)y2.z << 16) * v2;
            acc.w += __uint_as_float((unsigned)y2.w << 16) * v2;
            acc.x += __uint_as_float((unsigned)y3.x << 16) * v3;
            acc.y += __uint_as_float((unsigned)y3.y << 16) * v3;
            acc.z += __uint_as_float((unsigned)y3.z << 16) * v3;
            acc.w += __uint_as_float((unsigned)y3.w << 16) * v3;
        }
        for (; j < cnt; ++j) {
            int   cj = __builtin_amdgcn_readfirstlane(__shfl(q.x, j));
            float vj = __int_as_float(__builtin_amdgcn_readfirstlane(__shfl(q.y, j)));
            ushort4 y4 = *(const ushort4*)(Y + (size_t)cj * 256 + fo);
            acc.x += __uint_as_float((unsigned)y4.x << 16) * vj;
            acc.y += __uint_as_float((unsigned)y4.y << 16) * vj;
            acc.z += __uint_as_float((unsigned)y4.z << 16) * vj;
            acc.w += __uint_as_float((unsigned)y4.w << 16) * vj;
        }
    }
    float4 r;
    r.x = acc.x > 0.f ? acc.x : 0.f;
    r.y = acc.y > 0.f ? acc.y : 0.f;
    r.z = acc.z > 0.f ? acc.z : 0.f;
    r.w = acc.w > 0.f ? acc.w : 0.f;
    ((float4*)(H + (size_t)row * 256))[lane] = r;
}

// ===========================================================================

extern "C" void kernel_launch(void* const* d_in, const int* in_sizes, int n_in,
                              void* d_out, int out_size, void* d_ws, size_t ws_size,
                              hipStream_t stream) {
    const float* X    = (const float*)d_in[0];
    const int*   rows = (const int*)d_in[1];
    const int*   cols = (const int*)d_in[2];
    const float* vals = (const float*)d_in[3];
    const float* W    = (const float*)d_in[4];
    float*       H    = (float*)d_out;

    // Workspace layout (256-aligned):
    //   Y       @          0 : 51,200,000  bf16 [N,256]
    //   row_ptr @ 51,200,000 :    400,896  int [N+1]
    //   cedge   @ 51,600,896 : 25,600,000  int2 [E]  (row-sorted packed col,val)
    //   bcv     @ 77,200,896 : 25,600,000  int2 [E]  (bucket-split packed)
    //   gcnt    @102,800,896 :      1,024  int [NB]
    //   bbase   @102,801,920 :      1,024  int [NB+1]
    //   gcursor @102,802,944 :      1,024  int [NB]
    char* ws = (char*)d_ws;
    unsigned short* Y       = (unsigned short*)(ws);
    int*            row_ptr = (int*)(ws + 51200000);
    int2*           cedge   = (int2*)(ws + 51600896);
    int2*           bcv     = (int2*)(ws + 77200896);
    int*            gcnt    = (int*)(ws + 102800896);
    int*            bbase   = (int*)(ws + 102801920);
    int*            gcursor = (int*)(ws + 102802944);

    hipMemsetAsync(gcnt, 0, NB * sizeof(int), stream);

    bucket_hist<<<256, 256, 0, stream>>>(rows, gcnt, N_EDGES);
    bucket_scan<<<1, 256, 0, stream>>>(gcnt, bbase, gcursor, row_ptr);
    split_gemm<<<NSPLIT + NGEMM, 256, 0, stream>>>(
        rows, cols, vals, gcursor, bcv, X, W, Y, N_EDGES);
    bucket_to_csr<<<NB, 256, 0, stream>>>(bbase, bcv, row_ptr, cedge);

    spmm_gather_relu<<<(N_NODES + 3) / 4, 256, 0, stream>>>(Y, row_ptr, cedge, H);
}